// Round 8
// baseline (185.674 us; speedup 1.0000x reference)
//
#include <hip/hip_runtime.h>

#define NTOK 16384
#define DIM 256
#define NEXP 8
#define HID 512
#define CAP 5120      // per-expert slot capacity: 20 tiles x 256
#define CSTRIDE 16    // counts[e*CSTRIDE]: 64B apart

typedef unsigned short ushort_t;
typedef short bf16x8 __attribute__((ext_vector_type(8)));
typedef float f32x16 __attribute__((ext_vector_type(16)));

static __device__ __forceinline__ ushort_t f2bf(float f) {
    unsigned int u = __float_as_uint(f);
    unsigned int r = (u + 0x7FFFu + ((u >> 16) & 1u)) >> 16;
    return (ushort_t)r;
}
static __device__ __forceinline__ float bf2f(ushort_t u) {
    unsigned int x = ((unsigned int)u) << 16;
    return __uint_as_float(x);
}
// tanh-form GELU, exp2-folded + fast rcp: ~7 VALU ops, max |err| ~1e-3
static __device__ __forceinline__ float gelu_fast(float v) {
    float v2 = v * v;
    float u = v * __builtin_fmaf(v2, -0.1029407079f, -2.3022090196f);
    float e = __builtin_amdgcn_exp2f(u);
    return v * __builtin_amdgcn_rcpf(1.0f + e);
}

// ---------------- kernel T: transpose weights fp32->bf16, zero counts ----------------
__global__ void k_transpose(const float* __restrict__ w1, const float* __restrict__ w2,
                            ushort_t* __restrict__ w1t, ushort_t* __restrict__ w2t,
                            int* __restrict__ counts) {
    __shared__ ushort_t tile[64][72];
    if (blockIdx.x == 0 && threadIdx.x < NEXP * CSTRIDE) counts[threadIdx.x] = 0;
    int b = blockIdx.x;
    const float* src; ushort_t* dst; int R, C, e, t;
    if (b < 256) { e = b >> 5; t = b & 31; src = w1; dst = w1t + e * DIM * HID; R = DIM; C = HID; }
    else { b -= 256; e = b >> 5; t = b & 31; src = w2; dst = w2t + e * DIM * HID; R = HID; C = DIM; }
    size_t ebase = (size_t)e * DIM * HID;
    int tilesC = C >> 6;
    int rt = t / tilesC, ct = t % tilesC;
    for (int i = 0; i < 16; i++) {
        int flat = i * 256 + threadIdx.x;
        int lr = flat >> 6, lc = flat & 63;
        tile[lr][lc] = f2bf(src[ebase + (size_t)(rt * 64 + lr) * C + ct * 64 + lc]);
    }
    __syncthreads();
    for (int i = 0; i < 16; i++) {
        int flat = i * 256 + threadIdx.x;
        int lr = flat >> 6, lc = flat & 63;
        dst[(ct * 64 + lr) * R + rt * 64 + lc] = tile[lc][lr];
    }
}

// ---------------- kernel R: router + X->bf16 canonicalize (fused) ----------------
__global__ void k_router(const float* __restrict__ X, const float* __restrict__ Wg,
                         int* counts, int* tok_list, int* inv_idx, float* inv_w,
                         ushort_t* __restrict__ Xb) {
    __shared__ float xs[64][257];
    __shared__ float lg[64][8];
    __shared__ int te0[64], te1[64], lo0[64], lo1[64];
    __shared__ float tw0[64], tw1[64];
    __shared__ int lcnt[NEXP], gbase[NEXP];
    int tid = threadIdx.x;
    int tok0 = blockIdx.x * 64;
    if (tid < NEXP) lcnt[tid] = 0;
    for (int i = 0; i < 8; i++) {
        int flat = i * 256 + tid;
        int r = flat >> 5, c8 = (flat & 31) << 3;
        const float* row = X + (size_t)(tok0 + r) * DIM + c8;
        float4 a = *(const float4*)row;
        float4 b = *(const float4*)(row + 4);
        xs[r][c8 + 0] = a.x; xs[r][c8 + 1] = a.y; xs[r][c8 + 2] = a.z; xs[r][c8 + 3] = a.w;
        xs[r][c8 + 4] = b.x; xs[r][c8 + 5] = b.y; xs[r][c8 + 6] = b.z; xs[r][c8 + 7] = b.w;
    }
    __syncthreads();
    for (int i = 0; i < 8; i++) {
        int flat = i * 256 + tid;
        int r = flat >> 5, c8 = (flat & 31) << 3;
        ushort_t pk[8];
#pragma unroll
        for (int j = 0; j < 8; j++) pk[j] = f2bf(xs[r][c8 + j]);
        *(int4*)(Xb + (size_t)(tok0 + r) * DIM + c8) = *(const int4*)pk;
    }
    int tl = tid & 63, pair = tid >> 6;
    float l0 = 0.f, l1 = 0.f;
    for (int d = 0; d < DIM; d++) {
        float x = xs[tl][d];
        l0 += x * Wg[d * NEXP + 2 * pair];
        l1 += x * Wg[d * NEXP + 2 * pair + 1];
    }
    lg[tl][2 * pair] = l0; lg[tl][2 * pair + 1] = l1;
    __syncthreads();
    if (tid < 64) {
        float best = -1e30f; int bi = 0;
#pragma unroll
        for (int e = 0; e < NEXP; e++) { float v = lg[tid][e]; if (v > best) { best = v; bi = e; } }
        float best2 = -1e30f; int bi2 = 0;
#pragma unroll
        for (int e = 0; e < NEXP; e++) { if (e == bi) continue; float v = lg[tid][e]; if (v > best2) { best2 = v; bi2 = e; } }
        float ed = __expf(best2 - best);
        te0[tid] = bi; te1[tid] = bi2;
        tw0[tid] = 1.0f / (1.0f + ed);
        tw1[tid] = ed / (1.0f + ed);
        lo0[tid] = atomicAdd(&lcnt[bi], 1);
        lo1[tid] = atomicAdd(&lcnt[bi2], 1);
    }
    __syncthreads();
    if (tid < NEXP) gbase[tid] = atomicAdd(&counts[tid * CSTRIDE], lcnt[tid]);
    __syncthreads();
    if (tid < 64) {
        int token = tok0 + tid;
        int e0 = te0[tid], e1 = te1[tid];
        int p0 = gbase[e0] + lo0[tid]; if (p0 >= CAP) p0 = CAP - 1;
        int p1 = gbase[e1] + lo1[tid]; if (p1 >= CAP) p1 = CAP - 1;
        tok_list[e0 * CAP + p0] = token;
        tok_list[e1 * CAP + p1] = token;
        inv_idx[token * 2]     = (e0 << 16) | p0;  inv_w[token * 2]     = tw0[tid];
        inv_idx[token * 2 + 1] = (e1 << 16) | p1;  inv_w[token * 2 + 1] = tw1[tid];
    }
}

// ---------------- kernel M1: GEMM1 + GELU -> hb (32x32x16, token-register-blocked) ----------------
// grid: e(8) x tile(20: 256 tokens) x h-eighth(8: 64 h). Block: 256 thr / 4 waves.
// Wave: 64 tokens (2 tg) x 64 h (2 cf), K=256. LDS reads = 0.5/MFMA.
__launch_bounds__(256, 4)
__global__ void k_mlp1(const ushort_t* __restrict__ Xb, const ushort_t* __restrict__ w1t,
                       const float* __restrict__ b1,
                       const int* __restrict__ counts, const int* __restrict__ tok_list,
                       ushort_t* __restrict__ hb) {
    __shared__ ushort_t B1[64 * 264];   // [h][d], 33KB -> 4 blocks/CU
    int b = blockIdx.x;
    int e = b / 160;
    int rem = b % 160;
    int tile = rem >> 3, hq = rem & 7;
    int count = counts[e * CSTRIDE];
    if (count > CAP) count = CAP;
    int t0 = tile * 256;
    if (t0 >= count) return;

    int tid = threadIdx.x;
    int w = tid >> 6, l = tid & 63, m = l & 31, hi = l >> 5;

    const ushort_t* w1te = w1t + (size_t)e * DIM * HID + (size_t)hq * 64 * DIM;
#pragma unroll
    for (int i = 0; i < 8; i++) {
        int flat = i * 256 + tid;          // 2048 int4 = 64 rows x 32
        int hr = flat >> 5, c8 = (flat & 31) << 3;
        *(int4*)(B1 + hr * 264 + c8) = *(const int4*)(w1te + hr * DIM + c8);
    }
    int row0 = t0 + w * 64 + m;
    int row1 = row0 + 32;
    int ci0 = (row0 < count) ? row0 : (count - 1);
    int ci1 = (row1 < count) ? row1 : (count - 1);
    const ushort_t* x0 = Xb + (size_t)tok_list[e * CAP + ci0] * DIM + hi * 8;
    const ushort_t* x1 = Xb + (size_t)tok_list[e * CAP + ci1] * DIM + hi * 8;
    __syncthreads();

    f32x16 acc[2][2];
    acc[0][0] = (f32x16)(0.f); acc[0][1] = (f32x16)(0.f);
    acc[1][0] = (f32x16)(0.f); acc[1][1] = (f32x16)(0.f);
#pragma unroll
    for (int kc = 0; kc < 8; kc++) {       // 8 chunks x 32 k
        bf16x8 xk0[2], xk1[2];
        xk0[0] = *(const bf16x8*)(x0 + kc * 32);
        xk0[1] = *(const bf16x8*)(x0 + kc * 32 + 16);
        xk1[0] = *(const bf16x8*)(x1 + kc * 32);
        xk1[1] = *(const bf16x8*)(x1 + kc * 32 + 16);
#pragma unroll
        for (int ks = 0; ks < 2; ks++) {
#pragma unroll
            for (int cf = 0; cf < 2; cf++) {
                bf16x8 wfr = *(const bf16x8*)(B1 + (cf * 32 + m) * 264 + kc * 32 + ks * 16 + hi * 8);
                acc[0][cf] = __builtin_amdgcn_mfma_f32_32x32x16_bf16(wfr, xk0[ks], acc[0][cf], 0, 0, 0);
                acc[1][cf] = __builtin_amdgcn_mfma_f32_32x32x16_bf16(wfr, xk1[ks], acc[1][cf], 0, 0, 0);
            }
        }
    }
    // epilogue: C col=tok, row h=(r&3)+8*(r>>2)+4*hi within cf*32
#pragma unroll
    for (int tg = 0; tg < 2; tg++) {
        int arow = row0 + tg * 32;
        if (arow < count) {
            ushort_t* hrow = hb + ((size_t)e * CAP + arow) * HID + hq * 64;
#pragma unroll
            for (int cf = 0; cf < 2; cf++) {
#pragma unroll
                for (int rg = 0; rg < 4; rg++) {
                    int hoff = cf * 32 + 8 * rg + 4 * hi;
                    float4 bv = *(const float4*)(b1 + e * HID + hq * 64 + hoff);
                    ushort4 pk;
                    pk.x = f2bf(gelu_fast(acc[tg][cf][rg * 4 + 0] + bv.x));
                    pk.y = f2bf(gelu_fast(acc[tg][cf][rg * 4 + 1] + bv.y));
                    pk.z = f2bf(gelu_fast(acc[tg][cf][rg * 4 + 2] + bv.z));
                    pk.w = f2bf(gelu_fast(acc[tg][cf][rg * 4 + 3] + bv.w));
                    *(ushort4*)(hrow + hoff) = pk;
                }
            }
        }
    }
}

// ---------------- kernel M2: GEMM2 -> yb (32x32x16, token-register-blocked) ----------------
// grid: e(8) x tile(20: 256 tokens) x d-quarter(4: 64 d). Block: 256 thr / 4 waves.
// Wave: 64 tokens (2 tg) x 64 d (2 cf), K=512.
__launch_bounds__(256, 2)
__global__ void k_mlp2(const ushort_t* __restrict__ hb, const ushort_t* __restrict__ w2t,
                       const float* __restrict__ b2,
                       const int* __restrict__ counts, ushort_t* __restrict__ yb) {
    __shared__ ushort_t B2[64 * 520];    // [d][h], 66.5KB -> 2 blocks/CU
    int b = blockIdx.x;
    int e = b / 80;
    int rem = b % 80;
    int tile = rem >> 2, dq = rem & 3;
    int count = counts[e * CSTRIDE];
    if (count > CAP) count = CAP;
    int t0 = tile * 256;
    if (t0 >= count) return;

    int tid = threadIdx.x;
    int w = tid >> 6, l = tid & 63, m = l & 31, hi = l >> 5;

    const ushort_t* w2te = w2t + (size_t)e * DIM * HID + (size_t)dq * 64 * HID;
#pragma unroll
    for (int i = 0; i < 16; i++) {
        int flat = i * 256 + tid;          // 4096 int4 = 64 rows x 64
        int dr = flat >> 6, c8 = (flat & 63) << 3;
        *(int4*)(B2 + dr * 520 + c8) = *(const int4*)(w2te + dr * HID + c8);
    }
    int row0 = t0 + w * 64 + m;
    int row1 = row0 + 32;
    int ci0 = (row0 < count) ? row0 : (count - 1);
    int ci1 = (row1 < count) ? row1 : (count - 1);
    const ushort_t* h0 = hb + ((size_t)e * CAP + ci0) * HID + hi * 8;
    const ushort_t* h1 = hb + ((size_t)e * CAP + ci1) * HID + hi * 8;
    __syncthreads();

    f32x16 acc[2][2];
    acc[0][0] = (f32x16)(0.f); acc[0][1] = (f32x16)(0.f);
    acc[1][0] = (f32x16)(0.f); acc[1][1] = (f32x16)(0.f);
#pragma unroll
    for (int kc = 0; kc < 16; kc++) {      // 16 chunks x 32 k
        bf16x8 hf0[2], hf1[2];
        hf0[0] = *(const bf16x8*)(h0 + kc * 32);
        hf0[1] = *(const bf16x8*)(h0 + kc * 32 + 16);
        hf1[0] = *(const bf16x8*)(h1 + kc * 32);
        hf1[1] = *(const bf16x8*)(h1 + kc * 32 + 16);
#pragma unroll
        for (int ks = 0; ks < 2; ks++) {
#pragma unroll
            for (int cf = 0; cf < 2; cf++) {
                bf16x8 wfr = *(const bf16x8*)(B2 + (cf * 32 + m) * 520 + kc * 32 + ks * 16 + hi * 8);
                acc[0][cf] = __builtin_amdgcn_mfma_f32_32x32x16_bf16(wfr, hf0[ks], acc[0][cf], 0, 0, 0);
                acc[1][cf] = __builtin_amdgcn_mfma_f32_32x32x16_bf16(wfr, hf1[ks], acc[1][cf], 0, 0, 0);
            }
        }
    }
#pragma unroll
    for (int tg = 0; tg < 2; tg++) {
        int arow = row0 + tg * 32;
        if (arow < count) {
            ushort_t* yrow = yb + ((size_t)e * CAP + arow) * DIM + dq * 64;
#pragma unroll
            for (int cf = 0; cf < 2; cf++) {
#pragma unroll
                for (int rg = 0; rg < 4; rg++) {
                    int doff = cf * 32 + 8 * rg + 4 * hi;
                    float4 bv = *(const float4*)(b2 + e * DIM + dq * 64 + doff);
                    ushort4 pk;
                    pk.x = f2bf(acc[tg][cf][rg * 4 + 0] + bv.x);
                    pk.y = f2bf(acc[tg][cf][rg * 4 + 1] + bv.y);
                    pk.z = f2bf(acc[tg][cf][rg * 4 + 2] + bv.z);
                    pk.w = f2bf(acc[tg][cf][rg * 4 + 3] + bv.w);
                    *(ushort4*)(yrow + doff) = pk;
                }
            }
        }
    }
}

// ---------------- kernel F: combine y0*w0 + y1*w1 -> out (fp32) ----------------
__global__ void k_combine(const ushort_t* __restrict__ yb, const int* __restrict__ inv_idx,
                          const float* __restrict__ inv_w, float* __restrict__ out) {
    int tid = threadIdx.x;
    int n = blockIdx.x * 8 + (tid >> 5);
    int l32 = tid & 31, c8 = l32 << 3;
    int i0 = inv_idx[2 * n], i1 = inv_idx[2 * n + 1];
    float w0 = inv_w[2 * n], w1 = inv_w[2 * n + 1];
    size_t r0 = (size_t)(i0 >> 16) * CAP + (i0 & 0xFFFF);
    size_t r1 = (size_t)(i1 >> 16) * CAP + (i1 & 0xFFFF);
    int4 v0 = *(const int4*)(yb + r0 * DIM + c8);
    int4 v1 = *(const int4*)(yb + r1 * DIM + c8);
    ushort_t* p0 = (ushort_t*)&v0;
    ushort_t* p1 = (ushort_t*)&v1;
    float4 oa, ob;
    oa.x = w0 * bf2f(p0[0]) + w1 * bf2f(p1[0]);
    oa.y = w0 * bf2f(p0[1]) + w1 * bf2f(p1[1]);
    oa.z = w0 * bf2f(p0[2]) + w1 * bf2f(p1[2]);
    oa.w = w0 * bf2f(p0[3]) + w1 * bf2f(p1[3]);
    ob.x = w0 * bf2f(p0[4]) + w1 * bf2f(p1[4]);
    ob.y = w0 * bf2f(p0[5]) + w1 * bf2f(p1[5]);
    ob.z = w0 * bf2f(p0[6]) + w1 * bf2f(p1[6]);
    ob.w = w0 * bf2f(p0[7]) + w1 * bf2f(p1[7]);
    float4* op = (float4*)(out + (size_t)n * DIM + c8);
    op[0] = oa; op[1] = ob;
}

extern "C" void kernel_launch(void* const* d_in, const int* in_sizes, int n_in,
                              void* d_out, int out_size, void* d_ws, size_t ws_size,
                              hipStream_t stream) {
    const float* X  = (const float*)d_in[0];
    const float* Wg = (const float*)d_in[1];
    const float* w1 = (const float*)d_in[2];
    const float* b1 = (const float*)d_in[3];
    const float* w2 = (const float*)d_in[4];
    const float* b2 = (const float*)d_in[5];

    char* ws = (char*)d_ws;
    size_t off = 0;
    int* counts = (int*)(ws + off);        off = 1024;
    int* tok_list = (int*)(ws + off);      off += (size_t)NEXP * CAP * 4;        // 160KB
    int* inv_idx = (int*)(ws + off);       off += (size_t)NTOK * 2 * 4;          // 128KB
    float* inv_w = (float*)(ws + off);     off += (size_t)NTOK * 2 * 4;          // 128KB
    ushort_t* w1t = (ushort_t*)(ws + off); off += (size_t)NEXP * DIM * HID * 2;  // 2MB
    ushort_t* w2t = (ushort_t*)(ws + off); off += (size_t)NEXP * DIM * HID * 2;  // 2MB
    ushort_t* Xb = (ushort_t*)(ws + off);  off += (size_t)NTOK * DIM * 2;        // 8.4MB
    ushort_t* hb = (ushort_t*)(ws + off);  off += (size_t)NEXP * CAP * HID * 2;  // 41.9MB
    ushort_t* yb = (ushort_t*)(ws + off);  off += (size_t)NEXP * CAP * DIM * 2;  // 21MB

    k_transpose<<<512, 256, 0, stream>>>(w1, w2, w1t, w2t, counts);
    k_router<<<256, 256, 0, stream>>>(X, Wg, counts, tok_list, inv_idx, inv_w, Xb);
    k_mlp1<<<NEXP * 20 * 8, 256, 0, stream>>>(Xb, w1t, b1, counts, tok_list, hb);
    k_mlp2<<<NEXP * 20 * 4, 256, 0, stream>>>(hb, w2t, b2, counts, yb);
    k_combine<<<2048, 256, 0, stream>>>(yb, inv_idx, inv_w, (float*)d_out);
}

// Round 9
// 158.857 us; speedup vs baseline: 1.1688x; 1.1688x over previous
//
#include <hip/hip_runtime.h>

#define NTOK 16384
#define DIM 256
#define NEXP 8
#define HID 512
#define CAP 5120      // per-expert slot capacity
#define CSTRIDE 16    // counts[e*CSTRIDE]: 64B apart

typedef unsigned short ushort_t;
typedef short bf16x8 __attribute__((ext_vector_type(8)));
typedef float f32x4 __attribute__((ext_vector_type(4)));

static __device__ __forceinline__ ushort_t f2bf(float f) {
    unsigned int u = __float_as_uint(f);
    unsigned int r = (u + 0x7FFFu + ((u >> 16) & 1u)) >> 16;
    return (ushort_t)r;
}
static __device__ __forceinline__ float bf2f(ushort_t u) {
    unsigned int x = ((unsigned int)u) << 16;
    return __uint_as_float(x);
}
// tanh-form GELU, exp2-folded + fast rcp: ~7 VALU ops, max |err| ~1e-3
static __device__ __forceinline__ float gelu_fast(float v) {
    float v2 = v * v;
    float u = v * __builtin_fmaf(v2, -0.1029407079f, -2.3022090196f);
    float e = __builtin_amdgcn_exp2f(u);
    return v * __builtin_amdgcn_rcpf(1.0f + e);
}

// ---------------- kernel T: transpose weights fp32->bf16, zero counts ----------------
__global__ void k_transpose(const float* __restrict__ w1, const float* __restrict__ w2,
                            ushort_t* __restrict__ w1t, ushort_t* __restrict__ w2t,
                            int* __restrict__ counts) {
    __shared__ ushort_t tile[64][72];
    if (blockIdx.x == 0 && threadIdx.x < NEXP * CSTRIDE) counts[threadIdx.x] = 0;
    int b = blockIdx.x;
    const float* src; ushort_t* dst; int R, C, e, t;
    if (b < 256) { e = b >> 5; t = b & 31; src = w1; dst = w1t + e * DIM * HID; R = DIM; C = HID; }
    else { b -= 256; e = b >> 5; t = b & 31; src = w2; dst = w2t + e * DIM * HID; R = HID; C = DIM; }
    size_t ebase = (size_t)e * DIM * HID;
    int tilesC = C >> 6;
    int rt = t / tilesC, ct = t % tilesC;
    for (int i = 0; i < 16; i++) {
        int flat = i * 256 + threadIdx.x;
        int lr = flat >> 6, lc = flat & 63;
        tile[lr][lc] = f2bf(src[ebase + (size_t)(rt * 64 + lr) * C + ct * 64 + lc]);
    }
    __syncthreads();
    for (int i = 0; i < 16; i++) {
        int flat = i * 256 + threadIdx.x;
        int lr = flat >> 6, lc = flat & 63;
        dst[(ct * 64 + lr) * R + rt * 64 + lc] = tile[lc][lr];
    }
}

// ---------------- kernel R: router + X->bf16 canonicalize (fused) ----------------
__global__ void k_router(const float* __restrict__ X, const float* __restrict__ Wg,
                         int* counts, int* tok_list, int* inv_idx, float* inv_w,
                         ushort_t* __restrict__ Xb) {
    __shared__ float xs[64][257];
    __shared__ float lg[64][8];
    __shared__ int te0[64], te1[64], lo0[64], lo1[64];
    __shared__ float tw0[64], tw1[64];
    __shared__ int lcnt[NEXP], gbase[NEXP];
    int tid = threadIdx.x;
    int tok0 = blockIdx.x * 64;
    if (tid < NEXP) lcnt[tid] = 0;
    for (int i = 0; i < 8; i++) {
        int flat = i * 256 + tid;
        int r = flat >> 5, c8 = (flat & 31) << 3;
        const float* row = X + (size_t)(tok0 + r) * DIM + c8;
        float4 a = *(const float4*)row;
        float4 b = *(const float4*)(row + 4);
        xs[r][c8 + 0] = a.x; xs[r][c8 + 1] = a.y; xs[r][c8 + 2] = a.z; xs[r][c8 + 3] = a.w;
        xs[r][c8 + 4] = b.x; xs[r][c8 + 5] = b.y; xs[r][c8 + 6] = b.z; xs[r][c8 + 7] = b.w;
    }
    __syncthreads();
    for (int i = 0; i < 8; i++) {
        int flat = i * 256 + tid;
        int r = flat >> 5, c8 = (flat & 31) << 3;
        ushort_t pk[8];
#pragma unroll
        for (int j = 0; j < 8; j++) pk[j] = f2bf(xs[r][c8 + j]);
        *(int4*)(Xb + (size_t)(tok0 + r) * DIM + c8) = *(const int4*)pk;
    }
    int tl = tid & 63, pair = tid >> 6;
    float l0 = 0.f, l1 = 0.f;
    for (int d = 0; d < DIM; d++) {
        float x = xs[tl][d];
        l0 += x * Wg[d * NEXP + 2 * pair];
        l1 += x * Wg[d * NEXP + 2 * pair + 1];
    }
    lg[tl][2 * pair] = l0; lg[tl][2 * pair + 1] = l1;
    __syncthreads();
    if (tid < 64) {
        float best = -1e30f; int bi = 0;
#pragma unroll
        for (int e = 0; e < NEXP; e++) { float v = lg[tid][e]; if (v > best) { best = v; bi = e; } }
        float best2 = -1e30f; int bi2 = 0;
#pragma unroll
        for (int e = 0; e < NEXP; e++) { if (e == bi) continue; float v = lg[tid][e]; if (v > best2) { best2 = v; bi2 = e; } }
        float ed = __expf(best2 - best);
        te0[tid] = bi; te1[tid] = bi2;
        tw0[tid] = 1.0f / (1.0f + ed);
        tw1[tid] = ed / (1.0f + ed);
        lo0[tid] = atomicAdd(&lcnt[bi], 1);
        lo1[tid] = atomicAdd(&lcnt[bi2], 1);
    }
    __syncthreads();
    if (tid < NEXP) gbase[tid] = atomicAdd(&counts[tid * CSTRIDE], lcnt[tid]);
    __syncthreads();
    if (tid < 64) {
        int token = tok0 + tid;
        int e0 = te0[tid], e1 = te1[tid];
        int p0 = gbase[e0] + lo0[tid]; if (p0 >= CAP) p0 = CAP - 1;
        int p1 = gbase[e1] + lo1[tid]; if (p1 >= CAP) p1 = CAP - 1;
        tok_list[e0 * CAP + p0] = token;
        tok_list[e1 * CAP + p1] = token;
        inv_idx[token * 2]     = (e0 << 16) | p0;  inv_w[token * 2]     = tw0[tid];
        inv_idx[token * 2 + 1] = (e1 << 16) | p1;  inv_w[token * 2 + 1] = tw1[tid];
    }
}

// ---------------- kernel M1: GEMM1 + GELU -> hb (R6 structure) ----------------
// grid: e(8) x [hq(4) x tile(40)] (tile fast => co-resident blocks share w1t chunk).
// Block: 512 thr / 8 waves; wave = 16 tokens x 128 h, K=256; X frags pre-loop.
__launch_bounds__(512, 4)
__global__ void k_mlp1(const ushort_t* __restrict__ Xb, const ushort_t* __restrict__ w1t,
                       const float* __restrict__ b1,
                       const int* __restrict__ counts, const int* __restrict__ tok_list,
                       ushort_t* __restrict__ hb) {
    __shared__ ushort_t B1[128 * 264];   // [h][d], 67.5KB -> 2 blocks/CU
    int b = blockIdx.x;
    int e = b / 160;
    int rem = b % 160;
    int hq = rem / 40, tile = rem % 40;
    int count = counts[e * CSTRIDE];
    if (count > CAP) count = CAP;
    int t0 = tile * 128;
    if (t0 >= count) return;

    int tid = threadIdx.x;
    int w = tid >> 6, l = tid & 63, ln = l & 15, q = l >> 4;

    const ushort_t* w1te = w1t + (size_t)e * DIM * HID + (size_t)hq * 128 * DIM;
#pragma unroll
    for (int i = 0; i < 8; i++) {
        int flat = i * 512 + tid;
        int hr = flat >> 5, c8 = (flat & 31) << 3;
        *(int4*)(B1 + hr * 264 + c8) = *(const int4*)(w1te + hr * DIM + c8);
    }
    // X fragments (B-operand) pre-loop: 16 token rows per wave, K=256 in registers
    int arow = t0 + 16 * w + ln;
    int ci = (arow < count) ? arow : (count - 1);
    int atok = tok_list[e * CAP + ci];
    const ushort_t* xrow = Xb + (size_t)atok * DIM;
    bf16x8 xf[8];
#pragma unroll
    for (int ks = 0; ks < 8; ks++)
        xf[ks] = *(const bf16x8*)(xrow + ks * 32 + q * 8);
    __syncthreads();

    f32x4 zf = {0.f, 0.f, 0.f, 0.f};
    f32x4 acc[8];
#pragma unroll
    for (int i = 0; i < 8; i++) acc[i] = zf;
#pragma unroll
    for (int ks = 0; ks < 8; ks++) {
        bf16x8 xk = xf[ks];
#pragma unroll
        for (int cf = 0; cf < 8; cf++) {
            bf16x8 wfr = *(const bf16x8*)(B1 + (cf * 16 + ln) * 264 + ks * 32 + q * 8);
            acc[cf] = __builtin_amdgcn_mfma_f32_16x16x32_bf16(wfr, xk, acc[cf], 0, 0, 0);
        }
    }
    // epilogue: C[h=q*4+r (in-lane)][tok=ln]; bias float4; pack 4 bf16 -> 8B store
    size_t hrowbase = ((size_t)e * CAP + t0 + 16 * w + ln) * HID + hq * 128;
#pragma unroll
    for (int cf = 0; cf < 8; cf++) {
        float4 bv = *(const float4*)(b1 + e * HID + hq * 128 + cf * 16 + q * 4);
        ushort4 pk;
        pk.x = f2bf(gelu_fast(acc[cf][0] + bv.x));
        pk.y = f2bf(gelu_fast(acc[cf][1] + bv.y));
        pk.z = f2bf(gelu_fast(acc[cf][2] + bv.z));
        pk.w = f2bf(gelu_fast(acc[cf][3] + bv.w));
        *(ushort4*)(hb + hrowbase + cf * 16 + q * 4) = pk;
    }
}

// ---------------- kernel M2: GEMM2 -> yb (512 thr, 128-token tiles: halve staging) ----------------
// grid: e(8) x [dq(4) x tile(40)] (tile fast). Block: 512 thr / 8 waves.
// Wave: 16 tokens x 64 d, K=512; h frags pre-loop (af[16] = 64 VGPR).
__launch_bounds__(512, 2)
__global__ void k_mlp2(const ushort_t* __restrict__ hb, const ushort_t* __restrict__ w2t,
                       const float* __restrict__ b2,
                       const int* __restrict__ counts, ushort_t* __restrict__ yb) {
    __shared__ ushort_t B2[64 * 520];    // [d][h], 66.5KB -> 2 blocks/CU
    int b = blockIdx.x;
    int e = b / 160;
    int rem = b % 160;
    int dq = rem / 40, tile = rem % 40;
    int count = counts[e * CSTRIDE];
    if (count > CAP) count = CAP;
    int t0 = tile * 128;
    if (t0 >= count) return;

    int tid = threadIdx.x;
    int w = tid >> 6, l = tid & 63, ln = l & 15, q = l >> 4;

    const ushort_t* w2te = w2t + (size_t)e * DIM * HID + (size_t)dq * 64 * HID;
#pragma unroll
    for (int i = 0; i < 8; i++) {
        int flat = i * 512 + tid;           // 4096 int4 = 64 rows x 64
        int dr = flat >> 6, c8 = (flat & 63) << 3;
        *(int4*)(B2 + dr * 520 + c8) = *(const int4*)(w2te + dr * HID + c8);
    }
    // h fragments (B-operand) pre-loop: 16 rows per wave, K=512
    int arow = t0 + 16 * w + ln;
    int ci = (arow < count) ? arow : (count - 1);
    const ushort_t* hrow = hb + ((size_t)e * CAP + ci) * HID;
    bf16x8 af[16];
#pragma unroll
    for (int ks = 0; ks < 16; ks++)
        af[ks] = *(const bf16x8*)(hrow + ks * 32 + q * 8);
    __syncthreads();

    f32x4 zf = {0.f, 0.f, 0.f, 0.f};
    f32x4 acc[4];
#pragma unroll
    for (int i = 0; i < 4; i++) acc[i] = zf;
#pragma unroll
    for (int ks = 0; ks < 16; ks++) {
        bf16x8 hk = af[ks];
#pragma unroll
        for (int cf = 0; cf < 4; cf++) {
            bf16x8 wfr = *(const bf16x8*)(B2 + (cf * 16 + ln) * 520 + ks * 32 + q * 8);
            acc[cf] = __builtin_amdgcn_mfma_f32_16x16x32_bf16(wfr, hk, acc[cf], 0, 0, 0);
        }
    }
    // epilogue: C[d=q*4+r (in-lane)][tok=ln]; + b2; pack 4 bf16 -> 8B store
    size_t yrowbase = ((size_t)e * CAP + t0 + 16 * w + ln) * DIM + dq * 64;
#pragma unroll
    for (int cf = 0; cf < 4; cf++) {
        float4 bv = *(const float4*)(b2 + e * DIM + dq * 64 + cf * 16 + q * 4);
        ushort4 pk;
        pk.x = f2bf(acc[cf][0] + bv.x);
        pk.y = f2bf(acc[cf][1] + bv.y);
        pk.z = f2bf(acc[cf][2] + bv.z);
        pk.w = f2bf(acc[cf][3] + bv.w);
        *(ushort4*)(yb + yrowbase + cf * 16 + q * 4) = pk;
    }
}

// ---------------- kernel F: combine y0*w0 + y1*w1 -> out (fp32) ----------------
__global__ void k_combine(const ushort_t* __restrict__ yb, const int* __restrict__ inv_idx,
                          const float* __restrict__ inv_w, float* __restrict__ out) {
    int tid = threadIdx.x;
    int n = blockIdx.x * 8 + (tid >> 5);
    int l32 = tid & 31, c8 = l32 << 3;
    int i0 = inv_idx[2 * n], i1 = inv_idx[2 * n + 1];
    float w0 = inv_w[2 * n], w1 = inv_w[2 * n + 1];
    size_t r0 = (size_t)(i0 >> 16) * CAP + (i0 & 0xFFFF);
    size_t r1 = (size_t)(i1 >> 16) * CAP + (i1 & 0xFFFF);
    int4 v0 = *(const int4*)(yb + r0 * DIM + c8);
    int4 v1 = *(const int4*)(yb + r1 * DIM + c8);
    ushort_t* p0 = (ushort_t*)&v0;
    ushort_t* p1 = (ushort_t*)&v1;
    float4 oa, ob;
    oa.x = w0 * bf2f(p0[0]) + w1 * bf2f(p1[0]);
    oa.y = w0 * bf2f(p0[1]) + w1 * bf2f(p1[1]);
    oa.z = w0 * bf2f(p0[2]) + w1 * bf2f(p1[2]);
    oa.w = w0 * bf2f(p0[3]) + w1 * bf2f(p1[3]);
    ob.x = w0 * bf2f(p0[4]) + w1 * bf2f(p1[4]);
    ob.y = w0 * bf2f(p0[5]) + w1 * bf2f(p1[5]);
    ob.z = w0 * bf2f(p0[6]) + w1 * bf2f(p1[6]);
    ob.w = w0 * bf2f(p0[7]) + w1 * bf2f(p1[7]);
    float4* op = (float4*)(out + (size_t)n * DIM + c8);
    op[0] = oa; op[1] = ob;
}

extern "C" void kernel_launch(void* const* d_in, const int* in_sizes, int n_in,
                              void* d_out, int out_size, void* d_ws, size_t ws_size,
                              hipStream_t stream) {
    const float* X  = (const float*)d_in[0];
    const float* Wg = (const float*)d_in[1];
    const float* w1 = (const float*)d_in[2];
    const float* b1 = (const float*)d_in[3];
    const float* w2 = (const float*)d_in[4];
    const float* b2 = (const float*)d_in[5];

    char* ws = (char*)d_ws;
    size_t off = 0;
    int* counts = (int*)(ws + off);        off = 1024;
    int* tok_list = (int*)(ws + off);      off += (size_t)NEXP * CAP * 4;        // 160KB
    int* inv_idx = (int*)(ws + off);       off += (size_t)NTOK * 2 * 4;          // 128KB
    float* inv_w = (float*)(ws + off);     off += (size_t)NTOK * 2 * 4;          // 128KB
    ushort_t* w1t = (ushort_t*)(ws + off); off += (size_t)NEXP * DIM * HID * 2;  // 2MB
    ushort_t* w2t = (ushort_t*)(ws + off); off += (size_t)NEXP * DIM * HID * 2;  // 2MB
    ushort_t* Xb = (ushort_t*)(ws + off);  off += (size_t)NTOK * DIM * 2;        // 8.4MB
    ushort_t* hb = (ushort_t*)(ws + off);  off += (size_t)NEXP * CAP * HID * 2;  // 41.9MB
    ushort_t* yb = (ushort_t*)(ws + off);  off += (size_t)NEXP * CAP * DIM * 2;  // 21MB

    k_transpose<<<512, 256, 0, stream>>>(w1, w2, w1t, w2t, counts);
    k_router<<<256, 256, 0, stream>>>(X, Wg, counts, tok_list, inv_idx, inv_w, Xb);
    k_mlp1<<<NEXP * 40 * 4, 512, 0, stream>>>(Xb, w1t, b1, counts, tok_list, hb);
    k_mlp2<<<NEXP * 40 * 4, 512, 0, stream>>>(hb, w2t, b2, counts, yb);
    k_combine<<<2048, 256, 0, stream>>>(yb, inv_idx, inv_w, (float*)d_out);
}